// Round 20
// baseline (120.895 us; speedup 1.0000x reference)
//
#include <hip/hip_runtime.h>
#include <hip/hip_bf16.h>
#include <stdint.h>

typedef __attribute__((ext_vector_type(8))) short s16x8;
typedef __attribute__((ext_vector_type(4))) float f32x4;
typedef __attribute__((ext_vector_type(16))) float f32x16;

#define QSCALE 0.045084220027780106f  // (1/32) * log2(e), folded into Q projection

__device__ __forceinline__ unsigned short f2bf(float f) {
    union { float f; uint32_t u; } v; v.f = f;
    uint32_t u = v.u;
    u += 0x7FFFu + ((u >> 16) & 1u);   // round-to-nearest-even
    return (unsigned short)(u >> 16);
}

__device__ __forceinline__ unsigned int pkbf2(float a, float b) {
    union { __hip_bfloat162 h; unsigned int u; } x;
    x.h = __float22bfloat162_rn(float2{a, b});
    return x.u;
}

#define GLOAD_LDS16(gptr, lptr)                                                         \
    __builtin_amdgcn_global_load_lds(                                                   \
        (const __attribute__((address_space(1))) unsigned int*)(gptr),                  \
        (__attribute__((address_space(3))) unsigned int*)(lptr), 16, 0, 0)

// ---------------- fused fp32 -> bf16 conversion (all 7 tensors, 1 launch) ----------
__global__ __launch_bounds__(256)
void cvt_all(const float* __restrict__ q, const float* __restrict__ k,
             const float* __restrict__ v, const float* __restrict__ wq,
             const float* __restrict__ wk, const float* __restrict__ wv,
             const float* __restrict__ wo,
             unsigned short* __restrict__ xq, unsigned short* __restrict__ xk,
             unsigned short* __restrict__ xv, unsigned short* __restrict__ wqb,
             unsigned short* __restrict__ wkb, unsigned short* __restrict__ wvb,
             unsigned short* __restrict__ wob)
{
    int bid = blockIdx.x;
    const float* src; unsigned short* dst; int rel;
    if (bid < 6144) {
        int s = bid >> 11; rel = bid & 2047;
        src = (s == 0) ? q : (s == 1) ? k : v;
        dst = (s == 0) ? xq : (s == 1) ? xk : xv;
    } else {
        int s = (bid - 6144) >> 9; rel = (bid - 6144) & 511;
        src = (s == 0) ? wq : (s == 1) ? wk : (s == 2) ? wv : wo;
        dst = (s == 0) ? wqb : (s == 1) ? wkb : (s == 2) ? wvb : wob;
    }
    size_t i = (size_t)rel * 256 + threadIdx.x;
    const float4* p = (const float4*)src;
    float4 a = p[i * 2];
    float4 b2 = p[i * 2 + 1];
    s16x8 r;
    r[0] = (short)f2bf(a.x);  r[1] = (short)f2bf(a.y);
    r[2] = (short)f2bf(a.z);  r[3] = (short)f2bf(a.w);
    r[4] = (short)f2bf(b2.x); r[5] = (short)f2bf(b2.y);
    r[6] = (short)f2bf(b2.z); r[7] = (short)f2bf(b2.w);
    *(s16x8*)(dst + i * 8) = r;
}

// ---------------- NT GEMM, 512 threads / 8 waves (2M x 4N): C = A * Bt^T ------------
// mode 0: bf16 C (scaled); mode 1: f32 C; mode 2: Vt transposed write via LDS.
__device__ __forceinline__ void gemm_tile512(const unsigned short* __restrict__ A,
                                             const unsigned short* __restrict__ Bt,
                                             void* __restrict__ C,
                                             int N, int K, int mode, float cscale,
                                             unsigned short* Al, unsigned short* Bl,
                                             unsigned short* Tl)
{
    const int tid  = threadIdx.x;
    const int lane = tid & 63;
    const int w    = tid >> 6;          // 0..7
    const int wr   = w >> 2, wc = w & 3;
    const int l15  = lane & 15, l4 = lane >> 4;

    const int m0 = blockIdx.x * 128;
    const int n0 = blockIdx.y * 128;

    f32x4 acc[4][2];
#pragma unroll
    for (int i = 0; i < 4; ++i)
#pragma unroll
        for (int j = 0; j < 2; ++j) acc[i][j] = (f32x4){0.f, 0.f, 0.f, 0.f};

    const int slin = w * 64 + lane;
    const int srow = slin >> 2;
    const int scol = ((slin & 3) ^ ((srow >> 1) & 3)) * 8;

    int aoff[4], boff[2];
#pragma unroll
    for (int mi = 0; mi < 4; ++mi) {
        int rowa = wr * 64 + mi * 16 + l15;
        aoff[mi] = rowa * 32 + ((l4 ^ ((rowa >> 1) & 3)) * 8);
    }
#pragma unroll
    for (int nf = 0; nf < 2; ++nf) {
        int rowb = wc * 32 + nf * 16 + l15;
        boff[nf] = rowb * 32 + ((l4 ^ ((rowb >> 1) & 3)) * 8);
    }

    for (int k0 = 0; k0 < K; k0 += 32) {
        {
            const unsigned short* gA = A + (size_t)(m0 + srow) * K + k0 + scol;
            GLOAD_LDS16(gA, Al + w * 512);
            const unsigned short* gB = Bt + (size_t)(n0 + srow) * K + k0 + scol;
            GLOAD_LDS16(gB, Bl + w * 512);
        }
        __syncthreads();
        s16x8 af[4], bfr[2];
#pragma unroll
        for (int mi = 0; mi < 4; ++mi) af[mi] = *(const s16x8*)(Al + aoff[mi]);
#pragma unroll
        for (int nf = 0; nf < 2; ++nf) bfr[nf] = *(const s16x8*)(Bl + boff[nf]);
#pragma unroll
        for (int mi = 0; mi < 4; ++mi)
#pragma unroll
            for (int nf = 0; nf < 2; ++nf)
                acc[mi][nf] = __builtin_amdgcn_mfma_f32_16x16x32_bf16(af[mi], bfr[nf], acc[mi][nf], 0, 0, 0);
        __syncthreads();
    }

    if (mode == 2) {
        const int b_  = m0 >> 11;
        const int s0g = m0 & 2047;
#pragma unroll
        for (int c0 = 0; c0 < 128; c0 += 32) {
            if (wc == (c0 >> 5)) {
#pragma unroll
                for (int mi = 0; mi < 4; ++mi)
#pragma unroll
                    for (int nf = 0; nf < 2; ++nf) {
                        uint2 pw;
                        pw.x = pkbf2(acc[mi][nf][0], acc[mi][nf][1]);
                        pw.y = pkbf2(acc[mi][nf][2], acc[mi][nf][3]);
                        int c  = nf * 16 + l15;
                        int s4 = wr * 64 + mi * 16 + l4 * 4;
                        *(uint2*)&Tl[c * 136 + s4] = pw;
                    }
            }
            __syncthreads();
            {
                int d  = tid >> 4;          // 0..31
                int sg = tid & 15;
                s16x8 v = *(const s16x8*)&Tl[d * 136 + sg * 8];
                int colg  = n0 + c0 + d;
                int vtrow = (b_ * 16 + (colg >> 6)) * 64 + (colg & 63);
                *(s16x8*)((unsigned short*)C + (size_t)vtrow * 2048 + s0g + sg * 8) = v;
            }
            __syncthreads();
        }
        return;
    }

#pragma unroll
    for (int mi = 0; mi < 4; ++mi)
#pragma unroll
        for (int nf = 0; nf < 2; ++nf)
#pragma unroll
            for (int r = 0; r < 4; ++r) {
                int row = m0 + wr * 64 + mi * 16 + l4 * 4 + r;
                int col = n0 + wc * 32 + nf * 16 + l15;
                float v = acc[mi][nf][r];
                if (mode == 1) ((float*)C)[(size_t)row * N + col] = v;
                else           ((unsigned short*)C)[(size_t)row * N + col] = f2bf(v * cscale);
            }
}

__global__ __launch_bounds__(512, 6)
void gemm_qkv(const unsigned short* __restrict__ A0, const unsigned short* __restrict__ A1,
              const unsigned short* __restrict__ A2,
              const unsigned short* __restrict__ B0, const unsigned short* __restrict__ B1,
              const unsigned short* __restrict__ B2,
              unsigned short* __restrict__ C0, unsigned short* __restrict__ C1,
              unsigned short* __restrict__ C2)
{
    __shared__ unsigned short Al[128 * 32];
    __shared__ unsigned short Bl[128 * 32];
    __shared__ unsigned short Tl[32 * 136];
    int z = blockIdx.z;
    const unsigned short* A  = (z == 0) ? A0 : (z == 1) ? A1 : A2;
    const unsigned short* Bt = (z == 0) ? B0 : (z == 1) ? B1 : B2;
    unsigned short*       C  = (z == 0) ? C0 : (z == 1) ? C1 : C2;
    float cscale = (z == 0) ? QSCALE : 1.0f;
    int mode = (z == 2) ? 2 : 0;    // V projection writes Vt (transposed, coalesced)
    gemm_tile512(A, Bt, C, 1024, 1024, mode, cscale, Al, Bl, Tl);
}

// ---------------- gemm_out: 128x64 tiles, 2 blocks/CU (16 waves/CU) ----------------
__global__ __launch_bounds__(512, 4)
void gemm_out64(const unsigned short* __restrict__ A, const unsigned short* __restrict__ Bt,
                float* __restrict__ C)
{
    __shared__ unsigned short Al[128 * 32];   // 8 KB
    __shared__ unsigned short Bl[64 * 32];    // 4 KB

    const int tid  = threadIdx.x;
    const int lane = tid & 63;
    const int w    = tid >> 6;          // 0..7
    const int wr   = w >> 1, wc = w & 1;
    const int l15  = lane & 15, l4 = lane >> 4;

    const int m0 = blockIdx.x * 128;
    const int n0 = blockIdx.y * 64;
    const int N = 1024, K = 1024;

    f32x4 acc[2][2];
#pragma unroll
    for (int i = 0; i < 2; ++i)
#pragma unroll
        for (int j = 0; j < 2; ++j) acc[i][j] = (f32x4){0.f, 0.f, 0.f, 0.f};

    const int slin = w * 64 + lane;           // A: 512 granules
    const int srow = slin >> 2;
    const int scol = ((slin & 3) ^ ((srow >> 1) & 3)) * 8;
    const int brow = (w < 4) ? (slin >> 2) : 0;   // B: 256 granules (waves 0-3)
    const int bcol = ((slin & 3) ^ ((brow >> 1) & 3)) * 8;

    int aoff[2], boff[2];
#pragma unroll
    for (int mi = 0; mi < 2; ++mi) {
        int rowa = wr * 32 + mi * 16 + l15;
        aoff[mi] = rowa * 32 + ((l4 ^ ((rowa >> 1) & 3)) * 8);
    }
#pragma unroll
    for (int nf = 0; nf < 2; ++nf) {
        int rowb = wc * 32 + nf * 16 + l15;
        boff[nf] = rowb * 32 + ((l4 ^ ((rowb >> 1) & 3)) * 8);
    }

    for (int k0 = 0; k0 < K; k0 += 32) {
        {
            const unsigned short* gA = A + (size_t)(m0 + srow) * K + k0 + scol;
            GLOAD_LDS16(gA, Al + w * 512);
            if (w < 4) {
                const unsigned short* gB = Bt + (size_t)(n0 + brow) * K + k0 + bcol;
                GLOAD_LDS16(gB, Bl + w * 512);
            }
        }
        __syncthreads();
        s16x8 af[2], bfr[2];
#pragma unroll
        for (int mi = 0; mi < 2; ++mi) af[mi] = *(const s16x8*)(Al + aoff[mi]);
#pragma unroll
        for (int nf = 0; nf < 2; ++nf) bfr[nf] = *(const s16x8*)(Bl + boff[nf]);
#pragma unroll
        for (int mi = 0; mi < 2; ++mi)
#pragma unroll
            for (int nf = 0; nf < 2; ++nf)
                acc[mi][nf] = __builtin_amdgcn_mfma_f32_16x16x32_bf16(af[mi], bfr[nf], acc[mi][nf], 0, 0, 0);
        __syncthreads();
    }

#pragma unroll
    for (int mi = 0; mi < 2; ++mi)
#pragma unroll
        for (int nf = 0; nf < 2; ++nf)
#pragma unroll
            for (int r = 0; r < 4; ++r) {
                int row = m0 + wr * 32 + mi * 16 + l4 * 4 + r;
                int col = n0 + wc * 32 + nf * 16 + l15;
                C[(size_t)row * N + col] = acc[mi][nf][r];
            }
}

// ---------------- flash attention v8b: attn8 + deferred l-sum + setprio ------------
// 512 blocks x 512 threads, KV-split halves. 32x32x16 MFMA, in-register P hand-off.
// l accumulated in 8 independent lane-local f32x4 chains (off the critical path);
// reduced once in the epilogue. setprio(1) wraps the MFMA clusters (T5).
__global__ __launch_bounds__(512, 4)
void attn8(const unsigned short* __restrict__ Q,
           const unsigned short* __restrict__ Kp,
           const unsigned short* __restrict__ Vt,
           unsigned short* __restrict__ O)
{
    __shared__ unsigned short Kl[2][2][64 * 64];   // [half][dbuf][key][d]
    __shared__ unsigned short Vl[2][2][64 * 64];   // [half][dbuf][d][key]

    const int tid  = threadIdx.x;
    const int lane = tid & 63;
    const int w    = tid >> 6;
    const int half = w >> 2, ws = w & 3;
    const int q31  = lane & 31;
    const int lh   = lane >> 5;
    const int m7q  = q31 & 7;
    const int j2   = ((q31 >> 3) & 3) << 1;

    const int hw  = blockIdx.x;
    const int xcd = hw & 7;
    const int idx = hw >> 3;
    const int bh  = xcd * 4 + (idx >> 4);
    const int qt  = idx & 15;
    const int b = bh >> 4, hd = bh & 15;
    const int colbase = hd * 64;
    const int kvbase = half * 1024;

    const size_t qrow = (size_t)(b * 2048 + qt * 128 + ws * 32 + q31);
    s16x8 qf[4];
#pragma unroll
    for (int dk = 0; dk < 4; ++dk)
        qf[dk] = *(const s16x8*)(Q + qrow * 1024 + colbase + dk * 16 + lh * 8);

    int krow[2], kcol[2];
#pragma unroll
    for (int i = 0; i < 2; ++i) {
        int lin = (i * 4 + ws) * 64 + lane;
        krow[i] = lin >> 3;
        int u   = lin & 7;
        kcol[i] = ((u ^ (krow[i] & 7) ^ (((krow[i] >> 3) & 3) << 1)) * 8);
    }

    f32x16 oa[2] = {};
    f32x4 lv0 = {}, lv1 = {};   // deferred l accumulators (8 independent chains)

#define STAGE_KV(buf, kv0)                                                                     \
    {                                                                                          \
        _Pragma("unroll")                                                                      \
        for (int i = 0; i < 2; ++i) {                                                          \
            const unsigned short* gk = Kp + (size_t)(b * 2048 + (kv0) + krow[i]) * 1024        \
                                          + colbase + kcol[i];                                 \
            GLOAD_LDS16(gk, &Kl[half][buf][(i * 4 + ws) * 512]);                               \
            const unsigned short* gv = Vt + ((size_t)bh * 64 + krow[i]) * 2048                 \
                                          + (kv0) + kcol[i];                                   \
            GLOAD_LDS16(gv, &Vl[half][buf][(i * 4 + ws) * 512]);                               \
        }                                                                                      \
    }

    STAGE_KV(0, kvbase);
    __syncthreads();

    for (int kt = 0; kt < 16; ++kt) {
        const int cur = kt & 1;
        if (kt < 15) STAGE_KV(cur ^ 1, kvbase + (kt + 1) * 64);

        // ---- QK^T: S^T[key][q]
        f32x16 s0 = {}, s1 = {};
        __builtin_amdgcn_s_setprio(1);
#pragma unroll
        for (int dk = 0; dk < 4; ++dk) {
            const int sl = (((dk * 2 + lh) ^ m7q ^ j2) * 8);
            s16x8 kf0 = *(const s16x8*)(&Kl[half][cur][q31 * 64 + sl]);
            s16x8 kf1 = *(const s16x8*)(&Kl[half][cur][(32 + q31) * 64 + sl]);
            s0 = __builtin_amdgcn_mfma_f32_32x32x16_bf16(kf0, qf[dk], s0, 0, 0, 0);
            s1 = __builtin_amdgcn_mfma_f32_32x32x16_bf16(kf1, qf[dk], s1, 0, 0, 0);
        }
        __builtin_amdgcn_s_setprio(0);

        // ---- softmax numerator (no max-sub); l deferred into lane-local vectors
        unsigned int PK[2][8];
        {
            float p[16];
#pragma unroll
            for (int i = 0; i < 16; ++i) p[i] = __builtin_amdgcn_exp2f(s0[i]);
#pragma unroll
            for (int j = 0; j < 8; ++j) PK[0][j] = pkbf2(p[2 * j], p[2 * j + 1]);
            lv0 += (f32x4){p[0], p[1], p[2], p[3]};
            lv1 += (f32x4){p[4], p[5], p[6], p[7]};
            lv0 += (f32x4){p[8], p[9], p[10], p[11]};
            lv1 += (f32x4){p[12], p[13], p[14], p[15]};
#pragma unroll
            for (int i = 0; i < 16; ++i) p[i] = __builtin_amdgcn_exp2f(s1[i]);
#pragma unroll
            for (int j = 0; j < 8; ++j) PK[1][j] = pkbf2(p[2 * j], p[2 * j + 1]);
            lv0 += (f32x4){p[0], p[1], p[2], p[3]};
            lv1 += (f32x4){p[4], p[5], p[6], p[7]};
            lv0 += (f32x4){p[8], p[9], p[10], p[11]};
            lv1 += (f32x4){p[12], p[13], p[14], p[15]};
        }

        // ---- PV: P B-frag via shfl_xor(32)+select (R9-verified)
#pragma unroll
        for (int t = 0; t < 4; ++t) {
            const int bk = t >> 1, j0 = (t & 1) * 4;
            unsigned int A0 = PK[bk][j0],     C0 = PK[bk][j0 + 2];
            unsigned int A1 = PK[bk][j0 + 1], C1 = PK[bk][j0 + 3];
            unsigned int sA0 = (unsigned int)__shfl_xor((int)A0, 32, 64);
            unsigned int sC0 = (unsigned int)__shfl_xor((int)C0, 32, 64);
            unsigned int sA1 = (unsigned int)__shfl_xor((int)A1, 32, 64);
            unsigned int sC1 = (unsigned int)__shfl_xor((int)C1, 32, 64);
            union { unsigned int u[4]; s16x8 v; } pa;
            pa.u[0] = lh ? sC0 : A0;
            pa.u[1] = lh ? sC1 : A1;
            pa.u[2] = lh ? C0 : sA0;
            pa.u[3] = lh ? C1 : sA1;
            const int slv = (((t * 2 + lh) ^ m7q ^ j2) * 8);
            s16x8 vf0 = *(const s16x8*)(&Vl[half][cur][q31 * 64 + slv]);
            s16x8 vf1 = *(const s16x8*)(&Vl[half][cur][(32 + q31) * 64 + slv]);
            __builtin_amdgcn_s_setprio(1);
            oa[0] = __builtin_amdgcn_mfma_f32_32x32x16_bf16(vf0, pa.v, oa[0], 0, 0, 0);
            oa[1] = __builtin_amdgcn_mfma_f32_32x32x16_bf16(vf1, pa.v, oa[1], 0, 0, 0);
            __builtin_amdgcn_s_setprio(0);
        }
        __syncthreads();
    }

    // ---- epilogue: reduce deferred l, then cross-half merge
    f32x4 lv = lv0 + lv1;
    float l_run = (lv[0] + lv[1]) + (lv[2] + lv[3]);
    l_run += __shfl_xor(l_run, 32, 64);

    f32x4* Xch = (f32x4*)&Kl[0][0][0];
    float*  Lx = (float*)&Vl[0][0][0];

    if (half == 1) {
#pragma unroll
        for (int dh = 0; dh < 2; ++dh)
#pragma unroll
            for (int rg = 0; rg < 4; ++rg) {
                f32x4 c = { oa[dh][rg * 4 + 0], oa[dh][rg * 4 + 1],
                            oa[dh][rg * 4 + 2], oa[dh][rg * 4 + 3] };
                Xch[((ws * 8 + dh * 4 + rg) << 6) + lane] = c;
            }
        if (lh == 0) Lx[ws * 32 + q31] = l_run;
    }
    __syncthreads();
    if (half == 0) {
        const float lt  = l_run + Lx[ws * 32 + q31];
        const float inv = 1.0f / lt;
#pragma unroll
        for (int dh = 0; dh < 2; ++dh)
#pragma unroll
            for (int rg = 0; rg < 4; ++rg) {
                f32x4 po = Xch[((ws * 8 + dh * 4 + rg) << 6) + lane];
                const int d0 = dh * 32 + rg * 8 + lh * 4;
                uint2 pw;
                pw.x = pkbf2((oa[dh][rg * 4 + 0] + po[0]) * inv,
                             (oa[dh][rg * 4 + 1] + po[1]) * inv);
                pw.y = pkbf2((oa[dh][rg * 4 + 2] + po[2]) * inv,
                             (oa[dh][rg * 4 + 3] + po[3]) * inv);
                *(uint2*)(O + qrow * 1024 + colbase + d0) = pw;
            }
    }
#undef STAGE_KV
}

// ---------------- launch ----------------
extern "C" void kernel_launch(void* const* d_in, const int* in_sizes, int n_in,
                              void* d_out, int out_size, void* d_ws, size_t ws_size,
                              hipStream_t stream)
{
    const float* query = (const float*)d_in[0];
    const float* key   = (const float*)d_in[1];
    const float* value = (const float*)d_in[2];
    const float* Wq    = (const float*)d_in[3];
    const float* Wk    = (const float*)d_in[4];
    const float* Wv    = (const float*)d_in[5];
    const float* Wo    = (const float*)d_in[6];
    float* out = (float*)d_out;

    char* ws = (char*)d_ws;
    const size_t SZX = (size_t)4096 * 1024 * 2;  // 8 MiB
    const size_t SZW = (size_t)1024 * 1024 * 2;  // 2 MiB
    unsigned short* Xq  = (unsigned short*)(ws + 0);
    unsigned short* Xk  = (unsigned short*)(ws + SZX);
    unsigned short* Xv  = (unsigned short*)(ws + 2 * SZX);
    unsigned short* Wqb = (unsigned short*)(ws + 3 * SZX);
    unsigned short* Wkb = (unsigned short*)(ws + 3 * SZX + SZW);
    unsigned short* Wvb = (unsigned short*)(ws + 3 * SZX + 2 * SZW);
    unsigned short* Wob = (unsigned short*)(ws + 3 * SZX + 3 * SZW);
    unsigned short* Pq  = (unsigned short*)(ws + 3 * SZX + 4 * SZW);
    unsigned short* Pk  = (unsigned short*)(ws + 4 * SZX + 4 * SZW);
    unsigned short* Vt  = (unsigned short*)(ws + 5 * SZX + 4 * SZW);  // transposed V
    unsigned short* AO  = (unsigned short*)(ws + 6 * SZX + 4 * SZW);

    cvt_all<<<8192, 256, 0, stream>>>(query, key, value, Wq, Wk, Wv, Wo,
                                      Xq, Xk, Xv, Wqb, Wkb, Wvb, Wob);
    gemm_qkv<<<dim3(32, 8, 3), 512, 0, stream>>>(Xq, Xk, Xv, Wqb, Wkb, Wvb, Pq, Pk, Vt);
    attn8<<<512, 512, 0, stream>>>(Pq, Pk, Vt, AO);
    gemm_out64<<<dim3(32, 16), 512, 0, stream>>>(AO, Wob, out);
}

// Round 21
// 116.493 us; speedup vs baseline: 1.0378x; 1.0378x over previous
//
#include <hip/hip_runtime.h>
#include <hip/hip_bf16.h>
#include <stdint.h>

typedef __attribute__((ext_vector_type(8))) short s16x8;
typedef __attribute__((ext_vector_type(4))) float f32x4;

#define QSCALE 0.045084220027780106f  // (1/32) * log2(e), folded into Q projection

__device__ __forceinline__ unsigned short f2bf(float f) {
    union { float f; uint32_t u; } v; v.f = f;
    uint32_t u = v.u;
    u += 0x7FFFu + ((u >> 16) & 1u);   // round-to-nearest-even
    return (unsigned short)(u >> 16);
}

__device__ __forceinline__ unsigned int pkbf2(float a, float b) {
    union { __hip_bfloat162 h; unsigned int u; } x;
    x.h = __float22bfloat162_rn(float2{a, b});
    return x.u;
}

#define GLOAD_LDS16(gptr, lptr)                                                         \
    __builtin_amdgcn_global_load_lds(                                                   \
        (const __attribute__((address_space(1))) unsigned int*)(gptr),                  \
        (__attribute__((address_space(3))) unsigned int*)(lptr), 16, 0, 0)

// ---------------- fused fp32 -> bf16 conversion (all 7 tensors, 1 launch) ----------
__global__ __launch_bounds__(256)
void cvt_all(const float* __restrict__ q, const float* __restrict__ k,
             const float* __restrict__ v, const float* __restrict__ wq,
             const float* __restrict__ wk, const float* __restrict__ wv,
             const float* __restrict__ wo,
             unsigned short* __restrict__ xq, unsigned short* __restrict__ xk,
             unsigned short* __restrict__ xv, unsigned short* __restrict__ wqb,
             unsigned short* __restrict__ wkb, unsigned short* __restrict__ wvb,
             unsigned short* __restrict__ wob)
{
    int bid = blockIdx.x;
    const float* src; unsigned short* dst; int rel;
    if (bid < 6144) {
        int s = bid >> 11; rel = bid & 2047;
        src = (s == 0) ? q : (s == 1) ? k : v;
        dst = (s == 0) ? xq : (s == 1) ? xk : xv;
    } else {
        int s = (bid - 6144) >> 9; rel = (bid - 6144) & 511;
        src = (s == 0) ? wq : (s == 1) ? wk : (s == 2) ? wv : wo;
        dst = (s == 0) ? wqb : (s == 1) ? wkb : (s == 2) ? wvb : wob;
    }
    size_t i = (size_t)rel * 256 + threadIdx.x;
    const float4* p = (const float4*)src;
    float4 a = p[i * 2];
    float4 b2 = p[i * 2 + 1];
    s16x8 r;
    r[0] = (short)f2bf(a.x);  r[1] = (short)f2bf(a.y);
    r[2] = (short)f2bf(a.z);  r[3] = (short)f2bf(a.w);
    r[4] = (short)f2bf(b2.x); r[5] = (short)f2bf(b2.y);
    r[6] = (short)f2bf(b2.z); r[7] = (short)f2bf(b2.w);
    *(s16x8*)(dst + i * 8) = r;
}

// ---------------- NT GEMM, 512 threads / 8 waves (2M x 4N): C = A * Bt^T ------------
// mode 0: bf16 C (scaled); mode 1: f32 C; mode 2: Vt transposed write via LDS.
__device__ __forceinline__ void gemm_tile512(const unsigned short* __restrict__ A,
                                             const unsigned short* __restrict__ Bt,
                                             void* __restrict__ C,
                                             int N, int K, int mode, float cscale,
                                             unsigned short* Al, unsigned short* Bl,
                                             unsigned short* Tl)
{
    const int tid  = threadIdx.x;
    const int lane = tid & 63;
    const int w    = tid >> 6;          // 0..7
    const int wr   = w >> 2, wc = w & 3;
    const int l15  = lane & 15, l4 = lane >> 4;

    const int m0 = blockIdx.x * 128;
    const int n0 = blockIdx.y * 128;

    f32x4 acc[4][2];
#pragma unroll
    for (int i = 0; i < 4; ++i)
#pragma unroll
        for (int j = 0; j < 2; ++j) acc[i][j] = (f32x4){0.f, 0.f, 0.f, 0.f};

    const int slin = w * 64 + lane;
    const int srow = slin >> 2;
    const int scol = ((slin & 3) ^ ((srow >> 1) & 3)) * 8;

    int aoff[4], boff[2];
#pragma unroll
    for (int mi = 0; mi < 4; ++mi) {
        int rowa = wr * 64 + mi * 16 + l15;
        aoff[mi] = rowa * 32 + ((l4 ^ ((rowa >> 1) & 3)) * 8);
    }
#pragma unroll
    for (int nf = 0; nf < 2; ++nf) {
        int rowb = wc * 32 + nf * 16 + l15;
        boff[nf] = rowb * 32 + ((l4 ^ ((rowb >> 1) & 3)) * 8);
    }

    for (int k0 = 0; k0 < K; k0 += 32) {
        {
            const unsigned short* gA = A + (size_t)(m0 + srow) * K + k0 + scol;
            GLOAD_LDS16(gA, Al + w * 512);
            const unsigned short* gB = Bt + (size_t)(n0 + srow) * K + k0 + scol;
            GLOAD_LDS16(gB, Bl + w * 512);
        }
        __syncthreads();
        s16x8 af[4], bfr[2];
#pragma unroll
        for (int mi = 0; mi < 4; ++mi) af[mi] = *(const s16x8*)(Al + aoff[mi]);
#pragma unroll
        for (int nf = 0; nf < 2; ++nf) bfr[nf] = *(const s16x8*)(Bl + boff[nf]);
#pragma unroll
        for (int mi = 0; mi < 4; ++mi)
#pragma unroll
            for (int nf = 0; nf < 2; ++nf)
                acc[mi][nf] = __builtin_amdgcn_mfma_f32_16x16x32_bf16(af[mi], bfr[nf], acc[mi][nf], 0, 0, 0);
        __syncthreads();
    }

    if (mode == 2) {
        const int b_  = m0 >> 11;
        const int s0g = m0 & 2047;
#pragma unroll
        for (int c0 = 0; c0 < 128; c0 += 32) {
            if (wc == (c0 >> 5)) {
#pragma unroll
                for (int mi = 0; mi < 4; ++mi)
#pragma unroll
                    for (int nf = 0; nf < 2; ++nf) {
                        uint2 pw;
                        pw.x = pkbf2(acc[mi][nf][0], acc[mi][nf][1]);
                        pw.y = pkbf2(acc[mi][nf][2], acc[mi][nf][3]);
                        int c  = nf * 16 + l15;
                        int s4 = wr * 64 + mi * 16 + l4 * 4;
                        *(uint2*)&Tl[c * 136 + s4] = pw;
                    }
            }
            __syncthreads();
            {
                int d  = tid >> 4;          // 0..31
                int sg = tid & 15;
                s16x8 v = *(const s16x8*)&Tl[d * 136 + sg * 8];
                int colg  = n0 + c0 + d;
                int vtrow = (b_ * 16 + (colg >> 6)) * 64 + (colg & 63);
                *(s16x8*)((unsigned short*)C + (size_t)vtrow * 2048 + s0g + sg * 8) = v;
            }
            __syncthreads();
        }
        return;
    }

#pragma unroll
    for (int mi = 0; mi < 4; ++mi)
#pragma unroll
        for (int nf = 0; nf < 2; ++nf)
#pragma unroll
            for (int r = 0; r < 4; ++r) {
                int row = m0 + wr * 64 + mi * 16 + l4 * 4 + r;
                int col = n0 + wc * 32 + nf * 16 + l15;
                float v = acc[mi][nf][r];
                if (mode == 1) ((float*)C)[(size_t)row * N + col] = v;
                else           ((unsigned short*)C)[(size_t)row * N + col] = f2bf(v * cscale);
            }
}

__global__ __launch_bounds__(512, 6)
void gemm_qkv(const unsigned short* __restrict__ A0, const unsigned short* __restrict__ A1,
              const unsigned short* __restrict__ A2,
              const unsigned short* __restrict__ B0, const unsigned short* __restrict__ B1,
              const unsigned short* __restrict__ B2,
              unsigned short* __restrict__ C0, unsigned short* __restrict__ C1,
              unsigned short* __restrict__ C2)
{
    __shared__ unsigned short Al[128 * 32];
    __shared__ unsigned short Bl[128 * 32];
    __shared__ unsigned short Tl[32 * 136];
    int z = blockIdx.z;
    const unsigned short* A  = (z == 0) ? A0 : (z == 1) ? A1 : A2;
    const unsigned short* Bt = (z == 0) ? B0 : (z == 1) ? B1 : B2;
    unsigned short*       C  = (z == 0) ? C0 : (z == 1) ? C1 : C2;
    float cscale = (z == 0) ? QSCALE : 1.0f;
    int mode = (z == 2) ? 2 : 0;    // V projection writes Vt (transposed, coalesced)
    gemm_tile512(A, Bt, C, 1024, 1024, mode, cscale, Al, Bl, Tl);
}

// ---------------- gemm_out: 128x64 tiles, 2 blocks/CU (16 waves/CU) ----------------
__global__ __launch_bounds__(512, 4)
void gemm_out64(const unsigned short* __restrict__ A, const unsigned short* __restrict__ Bt,
                float* __restrict__ C)
{
    __shared__ unsigned short Al[128 * 32];   // 8 KB
    __shared__ unsigned short Bl[64 * 32];    // 4 KB

    const int tid  = threadIdx.x;
    const int lane = tid & 63;
    const int w    = tid >> 6;          // 0..7
    const int wr   = w >> 1, wc = w & 1;
    const int l15  = lane & 15, l4 = lane >> 4;

    const int m0 = blockIdx.x * 128;
    const int n0 = blockIdx.y * 64;
    const int N = 1024, K = 1024;

    f32x4 acc[2][2];
#pragma unroll
    for (int i = 0; i < 2; ++i)
#pragma unroll
        for (int j = 0; j < 2; ++j) acc[i][j] = (f32x4){0.f, 0.f, 0.f, 0.f};

    const int slin = w * 64 + lane;           // A: 512 granules
    const int srow = slin >> 2;
    const int scol = ((slin & 3) ^ ((srow >> 1) & 3)) * 8;
    const int brow = (w < 4) ? (slin >> 2) : 0;   // B: 256 granules (waves 0-3)
    const int bcol = ((slin & 3) ^ ((brow >> 1) & 3)) * 8;

    int aoff[2], boff[2];
#pragma unroll
    for (int mi = 0; mi < 2; ++mi) {
        int rowa = wr * 32 + mi * 16 + l15;
        aoff[mi] = rowa * 32 + ((l4 ^ ((rowa >> 1) & 3)) * 8);
    }
#pragma unroll
    for (int nf = 0; nf < 2; ++nf) {
        int rowb = wc * 32 + nf * 16 + l15;
        boff[nf] = rowb * 32 + ((l4 ^ ((rowb >> 1) & 3)) * 8);
    }

    for (int k0 = 0; k0 < K; k0 += 32) {
        {
            const unsigned short* gA = A + (size_t)(m0 + srow) * K + k0 + scol;
            GLOAD_LDS16(gA, Al + w * 512);
            if (w < 4) {
                const unsigned short* gB = Bt + (size_t)(n0 + brow) * K + k0 + bcol;
                GLOAD_LDS16(gB, Bl + w * 512);
            }
        }
        __syncthreads();
        s16x8 af[2], bfr[2];
#pragma unroll
        for (int mi = 0; mi < 2; ++mi) af[mi] = *(const s16x8*)(Al + aoff[mi]);
#pragma unroll
        for (int nf = 0; nf < 2; ++nf) bfr[nf] = *(const s16x8*)(Bl + boff[nf]);
#pragma unroll
        for (int mi = 0; mi < 2; ++mi)
#pragma unroll
            for (int nf = 0; nf < 2; ++nf)
                acc[mi][nf] = __builtin_amdgcn_mfma_f32_16x16x32_bf16(af[mi], bfr[nf], acc[mi][nf], 0, 0, 0);
        __syncthreads();
    }

#pragma unroll
    for (int mi = 0; mi < 2; ++mi)
#pragma unroll
        for (int nf = 0; nf < 2; ++nf)
#pragma unroll
            for (int r = 0; r < 4; ++r) {
                int row = m0 + wr * 32 + mi * 16 + l4 * 4 + r;
                int col = n0 + wc * 32 + nf * 16 + l15;
                C[(size_t)row * N + col] = acc[mi][nf][r];
            }
}

// ---------------- flash attention v5 (R8-measured 54.0 us, fastest attn variant) ----
// 512 blocks x 512 threads. Waves 0-3: keys [0,1024); waves 4-7: keys [1024,2048),
// same 128 q-rows. No-max softmax => partials combine linearly. 16x16x32 MFMA,
// P hand-off via wave-private swizzled LDS. + setprio around MFMA clusters (T5).
__global__ __launch_bounds__(512, 4)
void attn5(const unsigned short* __restrict__ Q,
           const unsigned short* __restrict__ Kp,
           const unsigned short* __restrict__ Vt,
           unsigned short* __restrict__ O)
{
    __shared__ unsigned short Kl[2][2][64 * 64];   // [half][dbuf][key][d]
    __shared__ unsigned short Vl[2][2][64 * 64];   // [half][dbuf][d][key]
    __shared__ unsigned short Pl[8][1024];         // per-wave [16 q][64 key], swizzled

    const int tid  = threadIdx.x;
    const int lane = tid & 63;
    const int w    = tid >> 6;
    const int half = w >> 2, ws = w & 3;
    const int l15  = lane & 15, l4 = lane >> 4;
    const int m7   = l15 & 7;

    const int hw  = blockIdx.x;
    const int xcd = hw & 7;
    const int idx = hw >> 3;
    const int bh  = xcd * 4 + (idx >> 4);
    const int qt  = idx & 15;
    const int b = bh >> 4, h = bh & 15;
    const int colbase = h * 64;
    const int kvbase = half * 1024;

    s16x8 qf[2][2];
    size_t rowQg[2];
#pragma unroll
    for (int g = 0; g < 2; ++g) {
        rowQg[g] = (size_t)(b * 2048 + qt * 128 + ws * 32 + g * 16 + l15);
#pragma unroll
        for (int kk = 0; kk < 2; ++kk)
            qf[g][kk] = *(const s16x8*)(Q + rowQg[g] * 1024 + colbase + kk * 32 + l4 * 8);
    }

    int krow[2], kcol[2];
#pragma unroll
    for (int i = 0; i < 2; ++i) {
        int lin = (i * 4 + ws) * 64 + lane;
        krow[i] = lin >> 3;
        kcol[i] = ((lin & 7) ^ (krow[i] & 7)) * 8;
    }

    f32x4 o_acc[2][4];
#pragma unroll
    for (int g = 0; g < 2; ++g)
#pragma unroll
        for (int df = 0; df < 4; ++df) o_acc[g][df] = (f32x4){0.f, 0.f, 0.f, 0.f};
    float l_run[2] = {0.f, 0.f};

#define STAGE_KV(buf, kv0)                                                                     \
    {                                                                                          \
        _Pragma("unroll")                                                                      \
        for (int i = 0; i < 2; ++i) {                                                          \
            const unsigned short* gk = Kp + (size_t)(b * 2048 + (kv0) + krow[i]) * 1024        \
                                          + colbase + kcol[i];                                 \
            GLOAD_LDS16(gk, &Kl[half][buf][(i * 4 + ws) * 512]);                               \
            const unsigned short* gv = Vt + ((size_t)bh * 64 + krow[i]) * 2048                 \
                                          + (kv0) + kcol[i];                                   \
            GLOAD_LDS16(gv, &Vl[half][buf][(i * 4 + ws) * 512]);                               \
        }                                                                                      \
    }

    STAGE_KV(0, kvbase);
    __syncthreads();

    for (int kt = 0; kt < 16; ++kt) {
        const int cur = kt & 1;
        if (kt < 15) STAGE_KV(cur ^ 1, kvbase + (kt + 1) * 64);

        // ---- QK^T (swapped): each K fragment feeds both q-groups
        f32x4 s[2][4];
#pragma unroll
        for (int g = 0; g < 2; ++g)
#pragma unroll
            for (int nf = 0; nf < 4; ++nf) s[g][nf] = (f32x4){0.f, 0.f, 0.f, 0.f};
        __builtin_amdgcn_s_setprio(1);
#pragma unroll
        for (int kk = 0; kk < 2; ++kk) {
            const int sl = ((kk * 4 + l4) ^ m7) * 8;
#pragma unroll
            for (int nf = 0; nf < 4; ++nf) {
                s16x8 kf = *(const s16x8*)(&Kl[half][cur][(nf * 16 + l15) * 64 + sl]);
                s[0][nf] = __builtin_amdgcn_mfma_f32_16x16x32_bf16(kf, qf[0][kk], s[0][nf], 0, 0, 0);
                s[1][nf] = __builtin_amdgcn_mfma_f32_16x16x32_bf16(kf, qf[1][kk], s[1][nf], 0, 0, 0);
            }
        }
        __builtin_amdgcn_s_setprio(0);

        // ---- softmax numerator (no max-sub) + P round-trip, g-sequential
        s16x8 pa[2][2];
#pragma unroll
        for (int g = 0; g < 2; ++g) {
            float p[4][4];
            float ps = 0.f;
#pragma unroll
            for (int nf = 0; nf < 4; ++nf)
#pragma unroll
                for (int r = 0; r < 4; ++r) {
                    p[nf][r] = __builtin_amdgcn_exp2f(s[g][nf][r]);
                    ps += p[nf][r];
                }
            l_run[g] += ps;
#pragma unroll
            for (int nf = 0; nf < 4; ++nf) {
                uint2 pw;
                pw.x = pkbf2(p[nf][0], p[nf][1]);
                pw.y = pkbf2(p[nf][2], p[nf][3]);
                *(uint2*)(&Pl[w][l15 * 64 + (((nf * 4 + l4) ^ (m7 << 1)) * 4)]) = pw;
            }
#pragma unroll
            for (int kk = 0; kk < 2; ++kk)
                pa[g][kk] = *(const s16x8*)(&Pl[w][l15 * 64 + (((kk * 4 + l4) ^ m7) * 8)]);
        }

        // ---- PV (swapped)
        __builtin_amdgcn_s_setprio(1);
#pragma unroll
        for (int kk = 0; kk < 2; ++kk) {
            const int sl = ((kk * 4 + l4) ^ m7) * 8;
#pragma unroll
            for (int df = 0; df < 4; ++df) {
                s16x8 vf = *(const s16x8*)(&Vl[half][cur][(df * 16 + l15) * 64 + sl]);
                o_acc[0][df] = __builtin_amdgcn_mfma_f32_16x16x32_bf16(vf, pa[0][kk], o_acc[0][df], 0, 0, 0);
                o_acc[1][df] = __builtin_amdgcn_mfma_f32_16x16x32_bf16(vf, pa[1][kk], o_acc[1][df], 0, 0, 0);
            }
        }
        __builtin_amdgcn_s_setprio(0);
        __syncthreads();
    }

    // ---- merge epilogue: half1 publishes partials via LDS; half0 combines + stores
    float lsum[2];
#pragma unroll
    for (int g = 0; g < 2; ++g) {
        lsum[g] = l_run[g];
        lsum[g] += __shfl_xor(lsum[g], 16, 64);
        lsum[g] += __shfl_xor(lsum[g], 32, 64);
    }

    f32x4* Xch = (f32x4*)&Kl[0][0][0];     // 32 KB: [ws*8 + g*4 + df][lane]
    float* Lx  = (float*)&Vl[0][0][0];     // [ws*2 + g][16]

    if (half == 1) {
#pragma unroll
        for (int g = 0; g < 2; ++g)
#pragma unroll
            for (int df = 0; df < 4; ++df)
                Xch[((ws * 8 + g * 4 + df) << 6) + lane] = o_acc[g][df];
        if (l4 == 0) {
            Lx[(ws * 2 + 0) * 16 + l15] = lsum[0];
            Lx[(ws * 2 + 1) * 16 + l15] = lsum[1];
        }
    }
    __syncthreads();
    if (half == 0) {
#pragma unroll
        for (int g = 0; g < 2; ++g) {
            float lt = lsum[g] + Lx[(ws * 2 + g) * 16 + l15];
            const float inv = 1.0f / lt;
#pragma unroll
            for (int df = 0; df < 4; ++df) {
                f32x4 po = Xch[((ws * 8 + g * 4 + df) << 6) + lane];
                uint2 pw;
                pw.x = pkbf2((o_acc[g][df][0] + po[0]) * inv, (o_acc[g][df][1] + po[1]) * inv);
                pw.y = pkbf2((o_acc[g][df][2] + po[2]) * inv, (o_acc[g][df][3] + po[3]) * inv);
                *(uint2*)(O + rowQg[g] * 1024 + colbase + df * 16 + l4 * 4) = pw;
            }
        }
    }
#undef STAGE_KV
}

// ---------------- launch ----------------
extern "C" void kernel_launch(void* const* d_in, const int* in_sizes, int n_in,
                              void* d_out, int out_size, void* d_ws, size_t ws_size,
                              hipStream_t stream)
{
    const float* query = (const float*)d_in[0];
    const float* key   = (const float*)d_in[1];
    const float* value = (const float*)d_in[2];
    const float* Wq    = (const float*)d_in[3];
    const float* Wk    = (const float*)d_in[4];
    const float* Wv    = (const float*)d_in[5];
    const float* Wo    = (const float*)d_in[6];
    float* out = (float*)d_out;

    char* ws = (char*)d_ws;
    const size_t SZX = (size_t)4096 * 1024 * 2;  // 8 MiB
    const size_t SZW = (size_t)1024 * 1024 * 2;  // 2 MiB
    unsigned short* Xq  = (unsigned short*)(ws + 0);
    unsigned short* Xk  = (unsigned short*)(ws + SZX);
    unsigned short* Xv  = (unsigned short*)(ws + 2 * SZX);
    unsigned short* Wqb = (unsigned short*)(ws + 3 * SZX);
    unsigned short* Wkb = (unsigned short*)(ws + 3 * SZX + SZW);
    unsigned short* Wvb = (unsigned short*)(ws + 3 * SZX + 2 * SZW);
    unsigned short* Wob = (unsigned short*)(ws + 3 * SZX + 3 * SZW);
    unsigned short* Pq  = (unsigned short*)(ws + 3 * SZX + 4 * SZW);
    unsigned short* Pk  = (unsigned short*)(ws + 4 * SZX + 4 * SZW);
    unsigned short* Vt  = (unsigned short*)(ws + 5 * SZX + 4 * SZW);  // transposed V
    unsigned short* AO  = (unsigned short*)(ws + 6 * SZX + 4 * SZW);

    cvt_all<<<8192, 256, 0, stream>>>(query, key, value, Wq, Wk, Wv, Wo,
                                      Xq, Xk, Xv, Wqb, Wkb, Wvb, Wob);
    gemm_qkv<<<dim3(32, 8, 3), 512, 0, stream>>>(Xq, Xk, Xv, Wqb, Wkb, Wvb, Pq, Pk, Vt);
    attn5<<<512, 512, 0, stream>>>(Pq, Pk, Vt, AO);
    gemm_out64<<<dim3(32, 16), 512, 0, stream>>>(AO, Wob, out);
}